// Round 4
// baseline (444.180 us; speedup 1.0000x reference)
//
#include <hip/hip_runtime.h>

#define B_  4
#define C_  64
#define H_  256
#define W_  256
#define HW_ 65536
#define NPIX_ (B_*HW_)        /* 262144 */
#define NELEM_ (B_*C_*HW_)    /* 16777216 */

typedef __attribute__((ext_vector_type(8))) short short8;
typedef __attribute__((ext_vector_type(4))) float floatx4;

static __device__ __forceinline__ unsigned short f2bf(float f){
  unsigned u = __float_as_uint(f);
  u += 0x7fff + ((u >> 16) & 1);          // RNE
  return (unsigned short)(u >> 16);
}
static __device__ __forceinline__ float bf2f(unsigned short s){
  return __uint_as_float(((unsigned)s) << 16);
}
static __device__ __forceinline__ unsigned pack2(float a, float b){
  return (unsigned)f2bf(a) | ((unsigned)f2bf(b) << 16);
}

// ---------------- K0: convert pw(192x64) + w2(64x64) to bf16 ----------------
__global__ __launch_bounds__(256) void k_cvt(
    const float* __restrict__ pw, const float* __restrict__ w2,
    unsigned short* __restrict__ wB)   // [0,12288): pwB, [12288,16384): w2B
{
  int i = blockIdx.x*256 + threadIdx.x;
  wB[i] = f2bf(i < 12288 ? pw[i] : w2[i - 12288]);
}

// ---------------- K1: dwconv 3x3 -> t[p][c] bf16 (pixel-major) --------------
__global__ __launch_bounds__(256) void k_dwconv(
    const float* __restrict__ x,
    const float* __restrict__ dwW,
    unsigned short* __restrict__ t)
{
  int tid = threadIdx.x;
  int bid = (blockIdx.x & 7) * 512 + (blockIdx.x >> 3);   // XCD-contiguous
  int b    = bid >> 10;
  int tile = bid & 1023;
  int h    = tile >> 2;
  int w0   = (tile & 3) << 6;
  int p  = tid & 63;            // pixel-in-tile
  int cg = tid >> 6;            // channel group (wave-uniform)
  int wg = w0 + p;

  unsigned pk[8];
#pragma unroll
  for (int i = 0; i < 16; ++i){
    int c = cg*16 + i;
    const float* xp = x + ((size_t)(b*C_ + c) << 16);
    const float* wp = dwW + c*9;                 // wave-uniform -> scalar loads
    float acc = 0.f;
#pragma unroll
    for (int dy = -1; dy <= 1; ++dy){
      int hy = h + dy;
      if ((unsigned)hy >= (unsigned)H_) continue;
      const float* row = xp + (hy << 8);
#pragma unroll
      for (int dx = -1; dx <= 1; ++dx){
        int wx = wg + dx;
        if ((unsigned)wx >= (unsigned)W_) continue;
        acc += wp[(dy+1)*3 + (dx+1)] * row[wx];
      }
    }
    unsigned short bv = f2bf(acc);
    if (i & 1) pk[i>>1] |= ((unsigned)bv << 16);
    else       pk[i>>1]  = (unsigned)bv;
  }
  size_t rowbase = ((size_t)bid*64 + p)*64 + cg*16;
  uint4 u0; u0.x = pk[0]; u0.y = pk[1]; u0.z = pk[2]; u0.w = pk[3];
  uint4 u1; u1.x = pk[4]; u1.y = pk[5]; u1.z = pk[6]; u1.w = pk[7];
  *(uint4*)(t + rowbase)     = u0;
  *(uint4*)(t + rowbase + 8) = u1;
}

// ---------------- K2: GEMM1  om[p][ch] = sum_c t[p][c]*pw[ch][c] ------------
// Swapped orientation: A = pwB (M=192 ch), B = t (N=16 px per wave).
// D: col(lane&15)=px, row(q*4+r)=ch -> 4 consecutive ch per acc -> 8B stores.
__global__ __launch_bounds__(256, 4) void k_gemm1(
    const unsigned short* __restrict__ t,
    const unsigned short* __restrict__ pwB,
    unsigned short* __restrict__ om)
{
  int tid = threadIdx.x;
  int wv = tid >> 6, lane = tid & 63;
  int mrow = lane & 15, q = lane >> 4;
  int px0 = blockIdx.x*64 + wv*16;

  floatx4 acc[12];
#pragma unroll
  for (int mt = 0; mt < 12; ++mt) acc[mt] = (floatx4){0.f,0.f,0.f,0.f};

#pragma unroll
  for (int kb = 0; kb < 2; ++kb){
    short8 bf = *(const short8*)(t + (size_t)(px0 + mrow)*64 + kb*32 + q*8);
#pragma unroll
    for (int mt = 0; mt < 12; ++mt){
      short8 af = *(const short8*)(pwB + (mt*16 + mrow)*64 + kb*32 + q*8);
      acc[mt] = __builtin_amdgcn_mfma_f32_16x16x32_bf16(af, bf, acc[mt], 0, 0, 0);
    }
  }

  size_t orow = (size_t)(px0 + mrow)*192;
#pragma unroll
  for (int mt = 0; mt < 12; ++mt){
    uint2 u; u.x = pack2(acc[mt][0], acc[mt][1]); u.y = pack2(acc[mt][2], acc[mt][3]);
    *(uint2*)(om + orow + mt*16 + q*4) = u;
  }
}

// ---------------- K3: deformable bilinear sampling -> sval[p][c] ------------
// Channel mapping: sy uses om[2c], sx uses om[2c+1], modulator om[128+c].
__global__ __launch_bounds__(256, 4) void k_sample(
    const float* __restrict__ x,
    const unsigned short* __restrict__ om,
    unsigned short* __restrict__ sval)
{
  int tid = threadIdx.x;
  int bid = (blockIdx.x & 7) * 512 + (blockIdx.x >> 3);   // XCD-contiguous
  int px = bid*64 + (tid >> 2);
  int cg = tid & 3;
  int b = px >> 16;
  int p = px & (HW_-1);
  int h = p >> 8, w = p & (W_-1);
  int c0 = cg*16;

  const uint4* ob = (const uint4*)(om + (size_t)px*192 + cg*32);
  uint4 oA = ob[0], oB = ob[1], oC = ob[2], oD = ob[3];   // 16 (oy,ox) pairs
  const uint4* mb = (const uint4*)(om + (size_t)px*192 + 128 + cg*16);
  uint4 mA = mb[0], mB = mb[1];                           // 16 modulator bf16

  unsigned pr[16] = {oA.x,oA.y,oA.z,oA.w, oB.x,oB.y,oB.z,oB.w,
                     oC.x,oC.y,oC.z,oC.w, oD.x,oD.y,oD.z,oD.w};
  unsigned md[8]  = {mA.x,mA.y,mA.z,mA.w, mB.x,mB.y,mB.z,mB.w};

  const float* xb = x + ((size_t)(b*C_) << 16);
  float hf = (float)h, wf = (float)w;
  unsigned pk[8];

#pragma unroll
  for (int i = 0; i < 16; ++i){
    int c = c0 + i;
    unsigned pair = pr[i];
    float oy = bf2f((unsigned short)(pair & 0xffffu));
    float ox = bf2f((unsigned short)(pair >> 16));
    float mm = bf2f((unsigned short)((md[i>>1] >> ((i&1)*16)) & 0xffffu));
    float mod = 2.f / (1.f + __expf(-mm));
    oy = fminf(fmaxf(oy, -64.f), 64.f);
    ox = fminf(fmaxf(ox, -64.f), 64.f);
    float sy = hf + oy, sx = wf + ox;
    float y0f = floorf(sy), x0f = floorf(sx);
    float wy = sy - y0f, wxr = sx - x0f;
    int y0 = (int)y0f, x0 = (int)x0f;
    const float* xc = xb + ((size_t)c << 16);
    bool y0v = ((unsigned)y0     < (unsigned)H_);
    bool y1v = ((unsigned)(y0+1) < (unsigned)H_);
    bool x0v = ((unsigned)x0     < (unsigned)W_);
    bool x1v = ((unsigned)(x0+1) < (unsigned)W_);
    int base0 = (y0 << 8) + x0;
    float v00 = (y0v && x0v) ? xc[base0]        : 0.f;
    float v01 = (y0v && x1v) ? xc[base0 + 1]    : 0.f;
    float v10 = (y1v && x0v) ? xc[base0 + W_]   : 0.f;
    float v11 = (y1v && x1v) ? xc[base0 + W_+1] : 0.f;
    float sres = (1.f-wy)*((1.f-wxr)*v00 + wxr*v01) + wy*((1.f-wxr)*v10 + wxr*v11);
    unsigned short bv = f2bf(sres * mod);
    if (i & 1) pk[i>>1] |= ((unsigned)bv << 16);
    else       pk[i>>1]  = (unsigned)bv;
  }

  size_t sbase = (size_t)px*64 + c0;
  uint4 u0; u0.x = pk[0]; u0.y = pk[1]; u0.z = pk[2]; u0.w = pk[3];
  uint4 u1; u1.x = pk[4]; u1.y = pk[5]; u1.z = pk[6]; u1.w = pk[7];
  *(uint4*)(sval + sbase)     = u0;
  *(uint4*)(sval + sbase + 8) = u1;
}

// ---------------- K4: GEMM2 + BN partial sums -------------------------------
// A = sval (M=16 px per wave), B = w2B (N=64 och). D: col=och, row=p ->
// 4 consecutive px per acc -> 8B stores into och-major out.
__global__ __launch_bounds__(256, 4) void k_gemm2(
    const unsigned short* __restrict__ sval,
    const unsigned short* __restrict__ w2B,
    unsigned short* __restrict__ outB,
    float* __restrict__ gsumS,
    float* __restrict__ gsqS)
{
  __shared__ float red1[4][64];
  __shared__ float red2[4][64];
  int tid = threadIdx.x;
  int wv = tid >> 6, lane = tid & 63;
  int mrow = lane & 15, q = lane >> 4;
  int px0 = blockIdx.x*64 + wv*16;

  floatx4 acc[4];
#pragma unroll
  for (int nt = 0; nt < 4; ++nt) acc[nt] = (floatx4){0.f,0.f,0.f,0.f};

#pragma unroll
  for (int kb = 0; kb < 2; ++kb){
    short8 af = *(const short8*)(sval + (size_t)(px0 + mrow)*64 + kb*32 + q*8);
#pragma unroll
    for (int nt = 0; nt < 4; ++nt){
      short8 bf = *(const short8*)(w2B + (nt*16 + mrow)*64 + kb*32 + q*8);
      acc[nt] = __builtin_amdgcn_mfma_f32_16x16x32_bf16(af, bf, acc[nt], 0, 0, 0);
    }
  }

  int b   = px0 >> 16;
  int hw0 = px0 & (HW_-1);
#pragma unroll
  for (int nt = 0; nt < 4; ++nt){
    int och = nt*16 + mrow;
    float a0 = acc[nt][0], a1 = acc[nt][1], a2 = acc[nt][2], a3 = acc[nt][3];
    uint2 u; u.x = pack2(a0, a1); u.y = pack2(a2, a3);
    *(uint2*)(outB + ((size_t)(b*C_ + och) << 16) + hw0 + q*4) = u;
    float s1 = a0 + a1 + a2 + a3;
    float s2 = a0*a0 + a1*a1 + a2*a2 + a3*a3;
    s1 += __shfl_xor(s1, 16, 64);  s2 += __shfl_xor(s2, 16, 64);
    s1 += __shfl_xor(s1, 32, 64);  s2 += __shfl_xor(s2, 32, 64);
    if (q == 0){ red1[wv][och] = s1; red2[wv][och] = s2; }
  }
  __syncthreads();
  if (tid < 64){
    float t1 = red1[0][tid] + red1[1][tid] + red1[2][tid] + red1[3][tid];
    float t2 = red2[0][tid] + red2[1][tid] + red2[2][tid] + red2[3][tid];
    int slot = blockIdx.x & 31;
    atomicAdd(&gsumS[slot*64 + tid], t1);
    atomicAdd(&gsqS[slot*64 + tid], t2);
  }
}

// ---------------- finalize BN stats into scale/shift ------------------------
__global__ void k_finalize(const float* __restrict__ gsumS, const float* __restrict__ gsqS,
                           const float* __restrict__ gamma, const float* __restrict__ beta,
                           float* __restrict__ scale, float* __restrict__ shift)
{
  int o = threadIdx.x;
  if (o < 64){
    float s1 = 0.f, s2 = 0.f;
    for (int s = 0; s < 32; ++s){ s1 += gsumS[s*64 + o]; s2 += gsqS[s*64 + o]; }
    float n = (float)NPIX_;
    float mean = s1 / n;
    float var  = s2 / n - mean*mean;          // biased, matches jnp.var
    float sc = gamma[o] * rsqrtf(var + 1e-5f);
    scale[o] = sc;
    shift[o] = beta[o] - mean*sc;
  }
}

// ---------------- K5: BN apply + exact GELU, 8 elems/thread -----------------
__global__ __launch_bounds__(256) void k_bn_gelu(
    const uint4* __restrict__ outB4,   // 8 bf16
    const float* __restrict__ scale,
    const float* __restrict__ shift,
    float4* __restrict__ y4)
{
  int i = blockIdx.x*256 + threadIdx.x;           // over NELEM_/8
  int och = (i >> 13) & 63;                       // (8i >> 16) & 63
  float sc = scale[och], sh = shift[och];
  uint4 u = outB4[i];
  float e[8];
  e[0] = bf2f((unsigned short)(u.x & 0xffffu)); e[1] = bf2f((unsigned short)(u.x >> 16));
  e[2] = bf2f((unsigned short)(u.y & 0xffffu)); e[3] = bf2f((unsigned short)(u.y >> 16));
  e[4] = bf2f((unsigned short)(u.z & 0xffffu)); e[5] = bf2f((unsigned short)(u.z >> 16));
  e[6] = bf2f((unsigned short)(u.w & 0xffffu)); e[7] = bf2f((unsigned short)(u.w >> 16));
  float4 o0, o1;
  float a;
  a = e[0]*sc + sh; o0.x = 0.5f*a*(1.f + erff(a*0.70710678118654752f));
  a = e[1]*sc + sh; o0.y = 0.5f*a*(1.f + erff(a*0.70710678118654752f));
  a = e[2]*sc + sh; o0.z = 0.5f*a*(1.f + erff(a*0.70710678118654752f));
  a = e[3]*sc + sh; o0.w = 0.5f*a*(1.f + erff(a*0.70710678118654752f));
  a = e[4]*sc + sh; o1.x = 0.5f*a*(1.f + erff(a*0.70710678118654752f));
  a = e[5]*sc + sh; o1.y = 0.5f*a*(1.f + erff(a*0.70710678118654752f));
  a = e[6]*sc + sh; o1.z = 0.5f*a*(1.f + erff(a*0.70710678118654752f));
  a = e[7]*sc + sh; o1.w = 0.5f*a*(1.f + erff(a*0.70710678118654752f));
  y4[2*i]   = o0;
  y4[2*i+1] = o1;
}

extern "C" void kernel_launch(void* const* d_in, const int* in_sizes, int n_in,
                              void* d_out, int out_size, void* d_ws, size_t ws_size,
                              hipStream_t stream)
{
  (void)in_sizes; (void)n_in; (void)out_size; (void)ws_size;
  const float* x     = (const float*)d_in[0];
  const float* dw    = (const float*)d_in[1];
  const float* pw    = (const float*)d_in[2];
  const float* w2    = (const float*)d_in[3];
  /* d_in[4] = bias: cancels exactly in BN (mean-subtracted), unused */
  const float* gamma = (const float*)d_in[5];
  const float* beta  = (const float*)d_in[6];

  // ws layout (total exactly 134,217,728 B — proven available):
  //   [0, 100663296)           om   (K2 w, K3 r); dead after K3:
  //        [0, 33554432)       outB (K4 w, K5 r)
  //        [96000000, +16896)  stats (memset after K3, K4 atomics)
  //   [100663296, 134217728)   t    (K1 w, K2 r); dead after K2:
  //                            sval (K3 w, K4 r) — exact overlay
  // bf16 weights live in d_out's tail 32KB (overwritten by K5 afterwards).
  char* ws = (char*)d_ws;
  unsigned short* om    = (unsigned short*)ws;
  unsigned short* outB  = (unsigned short*)ws;
  float*          stats = (float*)(ws + 96000000);
  float* gsumS = stats;                 // 32*64
  float* gsqS  = stats + 2048;          // 32*64
  float* scale = stats + 4096;
  float* shift = stats + 4160;
  unsigned short* t    = (unsigned short*)(ws + 100663296);
  unsigned short* sv   = t;
  unsigned short* wB   = (unsigned short*)((char*)d_out + 67076096);  // 32KB tail
  unsigned short* pwB  = wB;
  unsigned short* w2B  = wB + 12288;

  k_cvt     <<<64, 256, 0, stream>>>(pw, w2, wB);
  k_dwconv  <<<NPIX_/64, 256, 0, stream>>>(x, dw, t);
  k_gemm1   <<<NPIX_/64, 256, 0, stream>>>(t, pwB, om);
  k_sample  <<<NPIX_/64, 256, 0, stream>>>(x, om, sv);
  hipMemsetAsync(stats, 0, 16384, stream);        // zero gsum/gsq slots (om dead now)
  k_gemm2   <<<NPIX_/64, 256, 0, stream>>>(sv, w2B, outB, gsumS, gsqS);
  k_finalize<<<1, 64, 0, stream>>>(gsumS, gsqS, gamma, beta, scale, shift);
  k_bn_gelu <<<NELEM_/8/256, 256, 0, stream>>>((const uint4*)outB, scale, shift,
                                               (float4*)d_out);
}

// Round 5
// 315.322 us; speedup vs baseline: 1.4087x; 1.4087x over previous
//
#include <hip/hip_runtime.h>

#define B_  4
#define C_  64
#define H_  256
#define W_  256
#define HW_ 65536
#define NPIX_ (B_*HW_)        /* 262144 */
#define NELEM_ (B_*C_*HW_)    /* 16777216 */

#define OMS 200     /* bf16 om row stride in LDS (400B: 16B-aligned, bank cls 4) */
#define TS  72      /* bf16 sval row stride in LDS (144B: 16B-aligned) */

typedef __attribute__((ext_vector_type(8))) short short8;
typedef __attribute__((ext_vector_type(4))) float floatx4;

static __device__ __forceinline__ unsigned short f2bf(float f){
  unsigned u = __float_as_uint(f);
  u += 0x7fff + ((u >> 16) & 1);          // RNE
  return (unsigned short)(u >> 16);
}
static __device__ __forceinline__ float bf2f(unsigned short s){
  return __uint_as_float(((unsigned)s) << 16);
}
static __device__ __forceinline__ unsigned pack2(float a, float b){
  return (unsigned)f2bf(a) | ((unsigned)f2bf(b) << 16);
}

// ---------------- K0a: convert pw(192x64) + w2(64x64) to bf16 ---------------
__global__ __launch_bounds__(256) void k_cvtw(
    const float* __restrict__ pw, const float* __restrict__ w2,
    unsigned short* __restrict__ wB)   // [0,12288): pwB, [12288,16384): w2B
{
  int i = blockIdx.x*256 + threadIdx.x;
  wB[i] = f2bf(i < 12288 ? pw[i] : w2[i - 12288]);
}

// ---------------- K0b: convert x to bf16 ------------------------------------
__global__ __launch_bounds__(256) void k_cvtx(
    const float4* __restrict__ X4, uint2* __restrict__ Y)
{
  int i = blockIdx.x*256 + threadIdx.x;     // over NELEM_/4
  float4 a = X4[i];
  uint2 u; u.x = pack2(a.x, a.y); u.y = pack2(a.z, a.w);
  Y[i] = u;
}

// ---------------- K1: dwconv 3x3 (bf16 in) -> t[p][c] bf16 ------------------
__global__ __launch_bounds__(256) void k_dwconv(
    const unsigned short* __restrict__ xB,
    const float* __restrict__ dwW,
    unsigned short* __restrict__ t)
{
  int tid = threadIdx.x;
  int bid = ((blockIdx.x & 7) << 9) + (blockIdx.x >> 3);   // XCD-contiguous
  int b    = bid >> 10;
  int tile = bid & 1023;
  int h    = tile >> 2;
  int w0   = (tile & 3) << 6;
  int p  = tid & 63;
  int cg = tid >> 6;
  int wg = w0 + p;

  unsigned pk[8];
#pragma unroll
  for (int i = 0; i < 16; ++i){
    int c = cg*16 + i;
    const unsigned short* xp = xB + ((size_t)(b*C_ + c) << 16);
    const float* wp = dwW + c*9;                 // wave-uniform -> scalar loads
    float acc = 0.f;
#pragma unroll
    for (int dy = -1; dy <= 1; ++dy){
      int hy = h + dy;
      if ((unsigned)hy >= (unsigned)H_) continue;
      const unsigned short* row = xp + (hy << 8);
#pragma unroll
      for (int dx = -1; dx <= 1; ++dx){
        int wx = wg + dx;
        if ((unsigned)wx >= (unsigned)W_) continue;
        acc += wp[(dy+1)*3 + (dx+1)] * bf2f(row[wx]);
      }
    }
    unsigned short bv = f2bf(acc);
    if (i & 1) pk[i>>1] |= ((unsigned)bv << 16);
    else       pk[i>>1]  = (unsigned)bv;
  }
  size_t rowbase = ((size_t)bid*64 + p)*64 + cg*16;
  uint4 u0; u0.x = pk[0]; u0.y = pk[1]; u0.z = pk[2]; u0.w = pk[3];
  uint4 u1; u1.x = pk[4]; u1.y = pk[5]; u1.z = pk[6]; u1.w = pk[7];
  *(uint4*)(t + rowbase)     = u0;
  *(uint4*)(t + rowbase + 8) = u1;
}

// ---------------- K2: fused GEMM1 -> sample -> GEMM2 (+BN partials) ---------
// om and sval live only in LDS. Channel mapping: sy=om[2c], sx=om[2c+1],
// modulator=om[128+c]. Bias dropped (cancels in BN exactly).
__global__ __launch_bounds__(256, 4) void k_fuse(
    const unsigned short* __restrict__ xB,
    const unsigned short* __restrict__ t,
    const unsigned short* __restrict__ pwB,
    const unsigned short* __restrict__ w2B,
    unsigned short* __restrict__ outB,
    float* __restrict__ gsumS,
    float* __restrict__ gsqS)
{
  __shared__ __align__(16) char lds[27648];
  unsigned short* OM = (unsigned short*)lds;        // 64 x OMS bf16 (25600 B)
  unsigned short* T  = (unsigned short*)lds;        // 64 x TS bf16 (overlays OM)
  float* red1 = (float*)(lds + 25600);              // 4 x 64
  float* red2 = (float*)(lds + 25600 + 1024);       // 4 x 64

  int tid = threadIdx.x;
  int bid = ((blockIdx.x & 7) << 9) + (blockIdx.x >> 3);   // XCD-contiguous
  int wv = tid >> 6, lane = tid & 63;
  int mrow = lane & 15, q = lane >> 4;
  int px0 = bid*64;
  int pxw = px0 + wv*16;        // wave's pixel base (16 px per wave)

  // ---- phase A: GEMM1  om[px][ch] = sum_c t[px][c]*pw[ch][c] ----
  // A = pwB (M=192ch), B = t (N=16px). D: col(lane&15)=px, row(q*4+r)=ch.
  short8 bfrag[2];
#pragma unroll
  for (int kb = 0; kb < 2; ++kb)
    bfrag[kb] = *(const short8*)(t + (size_t)(pxw + mrow)*64 + kb*32 + q*8);

  floatx4 acc[12];
#pragma unroll
  for (int mt = 0; mt < 12; ++mt) acc[mt] = (floatx4){0.f,0.f,0.f,0.f};
#pragma unroll
  for (int kb = 0; kb < 2; ++kb)
#pragma unroll
    for (int mt = 0; mt < 12; ++mt){
      short8 af = *(const short8*)(pwB + (mt*16 + mrow)*64 + kb*32 + q*8);
      acc[mt] = __builtin_amdgcn_mfma_f32_16x16x32_bf16(af, bfrag[kb], acc[mt], 0, 0, 0);
    }

  {
    int omrow = (wv*16 + mrow)*OMS;
#pragma unroll
    for (int mt = 0; mt < 12; ++mt){
      uint2 u; u.x = pack2(acc[mt][0], acc[mt][1]); u.y = pack2(acc[mt][2], acc[mt][3]);
      *(uint2*)(OM + omrow + mt*16 + q*4) = u;
    }
  }
  __syncthreads();

  // ---- phase B: deformable bilinear sampling from bf16 x ----
  unsigned pk[8];
  {
    int pl = tid >> 2;          // block-local pixel
    int cg = tid & 3;
    int px = px0 + pl;
    int b = px >> 16;
    int p = px & (HW_-1);
    int h = p >> 8, w = p & (W_-1);
    int c0 = cg*16;

    const uint4* ob = (const uint4*)(OM + pl*OMS + cg*32);
    uint4 oA = ob[0], oB = ob[1], oC = ob[2], oD = ob[3];
    const uint4* mb = (const uint4*)(OM + pl*OMS + 128 + cg*16);
    uint4 mA = mb[0], mB = mb[1];
    unsigned pr[16] = {oA.x,oA.y,oA.z,oA.w, oB.x,oB.y,oB.z,oB.w,
                       oC.x,oC.y,oC.z,oC.w, oD.x,oD.y,oD.z,oD.w};
    unsigned md[8]  = {mA.x,mA.y,mA.z,mA.w, mB.x,mB.y,mB.z,mB.w};

    const unsigned short* xb = xB + ((size_t)(b*C_) << 16);
    float hf = (float)h, wf = (float)w;
#pragma unroll
    for (int i = 0; i < 16; ++i){
      int c = c0 + i;
      unsigned pair = pr[i];
      float oy = bf2f((unsigned short)(pair & 0xffffu));
      float ox = bf2f((unsigned short)(pair >> 16));
      float mm = bf2f((unsigned short)((md[i>>1] >> ((i&1)*16)) & 0xffffu));
      float mod = 2.f / (1.f + __expf(-mm));
      oy = fminf(fmaxf(oy, -64.f), 64.f);
      ox = fminf(fmaxf(ox, -64.f), 64.f);
      float sy = hf + oy, sx = wf + ox;
      float y0f = floorf(sy), x0f = floorf(sx);
      float wy = sy - y0f, wxr = sx - x0f;
      int y0 = (int)y0f, x0 = (int)x0f;
      bool y0v = ((unsigned)y0     < (unsigned)H_);
      bool y1v = ((unsigned)(y0+1) < (unsigned)H_);
      bool x0v = ((unsigned)x0     < (unsigned)W_);
      bool x1v = ((unsigned)(x0+1) < (unsigned)W_);
      int xc  = min(max(x0, 0), 254);        // pair start (always in-plane)
      bool x0lo = (x0 == xc);
      int yc0 = min(max(y0,   0), 255);
      int yc1 = min(max(y0+1, 0), 255);
      const unsigned short* xp = xb + ((size_t)c << 16);
      unsigned pu0, pu1;
      __builtin_memcpy(&pu0, xp + (yc0 << 8) + xc, 4);   // (y0 , x: xc..xc+1)
      __builtin_memcpy(&pu1, xp + (yc1 << 8) + xc, 4);   // (y0+1, same)
      float lo0 = bf2f((unsigned short)(pu0 & 0xffffu)), hi0 = bf2f((unsigned short)(pu0 >> 16));
      float lo1 = bf2f((unsigned short)(pu1 & 0xffffu)), hi1 = bf2f((unsigned short)(pu1 >> 16));
      float v00 = x0lo ? lo0 : hi0;  v00 = (x0v && y0v) ? v00 : 0.f;
      float v01 = x0lo ? hi0 : lo0;  v01 = (x1v && y0v) ? v01 : 0.f;
      float v10 = x0lo ? lo1 : hi1;  v10 = (x0v && y1v) ? v10 : 0.f;
      float v11 = x0lo ? hi1 : lo1;  v11 = (x1v && y1v) ? v11 : 0.f;
      float sres = (1.f-wy)*((1.f-wxr)*v00 + wxr*v01) + wy*((1.f-wxr)*v10 + wxr*v11);
      unsigned short bv = f2bf(sres * mod);
      if (i & 1) pk[i>>1] |= ((unsigned)bv << 16);
      else       pk[i>>1]  = (unsigned)bv;
    }
  }
  __syncthreads();              // all OM reads done before T overlays it

  {
    int pl = tid >> 2, cg = tid & 3;
    uint4 u0; u0.x = pk[0]; u0.y = pk[1]; u0.z = pk[2]; u0.w = pk[3];
    uint4 u1; u1.x = pk[4]; u1.y = pk[5]; u1.z = pk[6]; u1.w = pk[7];
    *(uint4*)(T + pl*TS + cg*16)     = u0;
    *(uint4*)(T + pl*TS + cg*16 + 8) = u1;
  }
  __syncthreads();

  // ---- phase C: GEMM2  out[px][och] = sum_c sval[px][c]*w2[och][c] ----
  // A = sval (M=16px), B = w2 (N=64och). D: col=och, row=px.
  short8 a2[2];
#pragma unroll
  for (int kb = 0; kb < 2; ++kb)
    a2[kb] = *(const short8*)(T + (wv*16 + mrow)*TS + kb*32 + q*8);

  floatx4 acc2[4];
#pragma unroll
  for (int nt = 0; nt < 4; ++nt) acc2[nt] = (floatx4){0.f,0.f,0.f,0.f};
#pragma unroll
  for (int kb = 0; kb < 2; ++kb)
#pragma unroll
    for (int nt = 0; nt < 4; ++nt){
      short8 bf = *(const short8*)(w2B + (nt*16 + mrow)*64 + kb*32 + q*8);
      acc2[nt] = __builtin_amdgcn_mfma_f32_16x16x32_bf16(a2[kb], bf, acc2[nt], 0, 0, 0);
    }

  int b   = pxw >> 16;
  int hw0 = pxw & (HW_-1);
#pragma unroll
  for (int nt = 0; nt < 4; ++nt){
    int och = nt*16 + mrow;
    float a0 = acc2[nt][0], a1 = acc2[nt][1], a2v = acc2[nt][2], a3 = acc2[nt][3];
    uint2 u; u.x = pack2(a0, a1); u.y = pack2(a2v, a3);
    *(uint2*)(outB + ((size_t)(b*C_ + och) << 16) + hw0 + q*4) = u;
    float s1 = a0 + a1 + a2v + a3;
    float s2 = a0*a0 + a1*a1 + a2v*a2v + a3*a3;
    s1 += __shfl_xor(s1, 16, 64);  s2 += __shfl_xor(s2, 16, 64);
    s1 += __shfl_xor(s1, 32, 64);  s2 += __shfl_xor(s2, 32, 64);
    if (q == 0){ red1[wv*64 + och] = s1; red2[wv*64 + och] = s2; }
  }
  __syncthreads();
  if (tid < 64){
    float t1 = red1[tid] + red1[64+tid] + red1[128+tid] + red1[192+tid];
    float t2 = red2[tid] + red2[64+tid] + red2[128+tid] + red2[192+tid];
    int slot = blockIdx.x & 31;
    atomicAdd(&gsumS[slot*64 + tid], t1);
    atomicAdd(&gsqS[slot*64 + tid], t2);
  }
}

// ---------------- finalize BN stats into scale/shift ------------------------
__global__ void k_finalize(const float* __restrict__ gsumS, const float* __restrict__ gsqS,
                           const float* __restrict__ gamma, const float* __restrict__ beta,
                           float* __restrict__ scale, float* __restrict__ shift)
{
  int o = threadIdx.x;
  if (o < 64){
    float s1 = 0.f, s2 = 0.f;
    for (int s = 0; s < 32; ++s){ s1 += gsumS[s*64 + o]; s2 += gsqS[s*64 + o]; }
    float n = (float)NPIX_;
    float mean = s1 / n;
    float var  = s2 / n - mean*mean;          // biased, matches jnp.var
    float sc = gamma[o] * rsqrtf(var + 1e-5f);
    scale[o] = sc;
    shift[o] = beta[o] - mean*sc;
  }
}

// ---------------- K5: BN apply + exact GELU, 8 elems/thread -----------------
__global__ __launch_bounds__(256) void k_bn_gelu(
    const uint4* __restrict__ outB4,   // 8 bf16
    const float* __restrict__ scale,
    const float* __restrict__ shift,
    float4* __restrict__ y4)
{
  int i = blockIdx.x*256 + threadIdx.x;           // over NELEM_/8
  int och = (i >> 13) & 63;                       // (8i >> 16) & 63
  float sc = scale[och], sh = shift[och];
  uint4 u = outB4[i];
  float e[8];
  e[0] = bf2f((unsigned short)(u.x & 0xffffu)); e[1] = bf2f((unsigned short)(u.x >> 16));
  e[2] = bf2f((unsigned short)(u.y & 0xffffu)); e[3] = bf2f((unsigned short)(u.y >> 16));
  e[4] = bf2f((unsigned short)(u.z & 0xffffu)); e[5] = bf2f((unsigned short)(u.z >> 16));
  e[6] = bf2f((unsigned short)(u.w & 0xffffu)); e[7] = bf2f((unsigned short)(u.w >> 16));
  float4 o0, o1;
  float a;
  a = e[0]*sc + sh; o0.x = 0.5f*a*(1.f + erff(a*0.70710678118654752f));
  a = e[1]*sc + sh; o0.y = 0.5f*a*(1.f + erff(a*0.70710678118654752f));
  a = e[2]*sc + sh; o0.z = 0.5f*a*(1.f + erff(a*0.70710678118654752f));
  a = e[3]*sc + sh; o0.w = 0.5f*a*(1.f + erff(a*0.70710678118654752f));
  a = e[4]*sc + sh; o1.x = 0.5f*a*(1.f + erff(a*0.70710678118654752f));
  a = e[5]*sc + sh; o1.y = 0.5f*a*(1.f + erff(a*0.70710678118654752f));
  a = e[6]*sc + sh; o1.z = 0.5f*a*(1.f + erff(a*0.70710678118654752f));
  a = e[7]*sc + sh; o1.w = 0.5f*a*(1.f + erff(a*0.70710678118654752f));
  y4[2*i]   = o0;
  y4[2*i+1] = o1;
}

extern "C" void kernel_launch(void* const* d_in, const int* in_sizes, int n_in,
                              void* d_out, int out_size, void* d_ws, size_t ws_size,
                              hipStream_t stream)
{
  (void)in_sizes; (void)n_in; (void)out_size; (void)ws_size;
  const float* x     = (const float*)d_in[0];
  const float* dw    = (const float*)d_in[1];
  const float* pw    = (const float*)d_in[2];
  const float* w2    = (const float*)d_in[3];
  /* d_in[4] = bias: cancels exactly in BN (mean-subtracted), unused */
  const float* gamma = (const float*)d_in[5];
  const float* beta  = (const float*)d_in[6];

  // ws layout (104 MB used of 128 MB):
  //   [0,          33554432)  xB    bf16 x
  //   [33554432,   67108864)  t     bf16 dwconv out [px][c]
  //   [67108864,  100663296)  outB  bf16 conv2 out, och-major
  //   [100663296, 100680192)  stats (gsumS 8K, gsqS 8K, scale/shift)
  //   [100680192, 100712960)  wB    bf16 weights (pw 24K, w2 8K)
  char* ws = (char*)d_ws;
  unsigned short* xB    = (unsigned short*)ws;
  unsigned short* t     = (unsigned short*)(ws + 33554432);
  unsigned short* outB  = (unsigned short*)(ws + 67108864);
  float*          stats = (float*)(ws + 100663296);
  float* gsumS = stats;                 // 32 slots x 64
  float* gsqS  = stats + 2048;
  float* scale = stats + 4096;
  float* shift = stats + 4160;
  unsigned short* wB  = (unsigned short*)(ws + 100680192);
  unsigned short* pwB = wB;
  unsigned short* w2B = wB + 12288;

  k_cvtw    <<<64, 256, 0, stream>>>(pw, w2, wB);
  k_cvtx    <<<NELEM_/4/256, 256, 0, stream>>>((const float4*)x, (uint2*)xB);
  hipMemsetAsync(stats, 0, 16384, stream);        // zero gsum/gsq slots
  k_dwconv  <<<NPIX_/64, 256, 0, stream>>>(xB, dw, t);
  k_fuse    <<<NPIX_/64, 256, 0, stream>>>(xB, t, pwB, w2B, outB, gsumS, gsqS);
  k_finalize<<<1, 64, 0, stream>>>(gsumS, gsqS, gamma, beta, scale, shift);
  k_bn_gelu <<<NELEM_/8/256, 256, 0, stream>>>((const uint4*)outB, scale, shift,
                                               (float4*)d_out);
}